// Round 3
// baseline (414.115 us; speedup 1.0000x reference)
//
#include <hip/hip_runtime.h>

typedef float floatx4 __attribute__((ext_vector_type(4)));
typedef short shortx8 __attribute__((ext_vector_type(8)));

#define T_SEQ 2048
#define NQH   32
#define NKVH  8
#define HD    64
#define DM    2048
#define NTOT  3072

__device__ __forceinline__ unsigned short f2bf(float f) {
    unsigned int u = __builtin_bit_cast(unsigned int, f);
    u += 0x7FFFu + ((u >> 16) & 1u);          // RNE
    return (unsigned short)(u >> 16);
}
__device__ __forceinline__ unsigned int pk2bf(float a, float b) {
    return (unsigned int)f2bf(a) | ((unsigned int)f2bf(b) << 16);
}

// async global->LDS, 16B per lane; LDS dest = wave-uniform base + lane*16
__device__ __forceinline__ void dma16(const unsigned short* g, unsigned short* l) {
    __builtin_amdgcn_global_load_lds(
        (const __attribute__((address_space(1))) unsigned int*)g,
        (__attribute__((address_space(3))) unsigned int*)l,
        16, 0, 0);
}

// ---------------------------------------------------------------------------
// x fp32 -> bf16 (into d_out scratch). 4096 blocks x 256 thr x 8 elems.
// ---------------------------------------------------------------------------
__global__ __launch_bounds__(256) void cvt_x(const float* __restrict__ x,
                                             unsigned short* __restrict__ xb) {
    size_t i = ((size_t)blockIdx.x * 256 + threadIdx.x) * 8;
    float4 a = *(const float4*)(x + i);
    float4 b = *(const float4*)(x + i + 4);
    uint4 o;
    o.x = pk2bf(a.x, a.y); o.y = pk2bf(a.z, a.w);
    o.z = pk2bf(b.x, b.y); o.w = pk2bf(b.z, b.w);
    *(uint4*)(xb + i) = o;
}

// ---------------------------------------------------------------------------
// W [k][n] fp32 -> Wt [n][k] bf16, rows 0-2047 = Wq^T, 2048-2559 = Wk^T,
// 2560-3071 = Wv^T. 64x64 tiles via LDS.
// ---------------------------------------------------------------------------
__global__ __launch_bounds__(256) void cvt_wt(const float* __restrict__ Wq,
                                              const float* __restrict__ Wk,
                                              const float* __restrict__ Wv,
                                              unsigned short* __restrict__ wt) {
    __shared__ __align__(16) unsigned short Ts[64][72];
    const int k0 = blockIdx.x * 64, n0g = blockIdx.y * 64;
    const float* W; int ldW, col0;
    if (n0g < 2048)      { W = Wq; ldW = 2048; col0 = n0g; }
    else if (n0g < 2560) { W = Wk; ldW = 512;  col0 = n0g - 2048; }
    else                 { W = Wv; ldW = 512;  col0 = n0g - 2560; }
    const int t = threadIdx.x;
    {
        int r = t >> 2, c = (t & 3) * 16;
        const float* src = W + (size_t)(k0 + r) * ldW + col0 + c;
        float4 v0 = *(const float4*)(src);
        float4 v1 = *(const float4*)(src + 4);
        float4 v2 = *(const float4*)(src + 8);
        float4 v3 = *(const float4*)(src + 12);
        uint4 o0 = {pk2bf(v0.x, v0.y), pk2bf(v0.z, v0.w), pk2bf(v1.x, v1.y), pk2bf(v1.z, v1.w)};
        uint4 o1 = {pk2bf(v2.x, v2.y), pk2bf(v2.z, v2.w), pk2bf(v3.x, v3.y), pk2bf(v3.z, v3.w)};
        *(uint4*)&Ts[r][c]     = o0;
        *(uint4*)&Ts[r][c + 8] = o1;
    }
    __syncthreads();
    {
        int n = t >> 2, kc = (t & 3) * 16;
        unsigned int dw[8];
        #pragma unroll
        for (int i = 0; i < 8; i++)
            dw[i] = (unsigned int)Ts[kc + 2 * i][n] | ((unsigned int)Ts[kc + 2 * i + 1][n] << 16);
        uint4 o0 = {dw[0], dw[1], dw[2], dw[3]}, o1 = {dw[4], dw[5], dw[6], dw[7]};
        unsigned short* d = wt + (size_t)(n0g + n) * DM + k0 + kc;
        *(uint4*)d = o0; *(uint4*)(d + 8) = o1;
    }
}

// ---------------------------------------------------------------------------
// Fused QKV GEMM, all-bf16, m97 structure: global_load_lds width=16, BK=64,
// XOR-swizzled unpadded LDS tiles (LDS[row][c] = G[row][c ^ (row&7)], 16B
// groups), 128x128 tile, 4 waves, 4x4 of 16x16x32 MFMA per wave.
// Q scale = 0.125*log2(e) folded (attention uses exp2).
// ---------------------------------------------------------------------------
__global__ __launch_bounds__(256) void qkv_gemm(
    const unsigned short* __restrict__ xb,   // [4096][2048]
    const unsigned short* __restrict__ wt,   // [3072][2048]
    unsigned short* __restrict__ Qws, unsigned short* __restrict__ Kws,
    unsigned short* __restrict__ Vws)
{
    __shared__ __align__(16) unsigned short At[128 * 64];
    __shared__ __align__(16) unsigned short Bt[128 * 64];

    const int tid = threadIdx.x;
    const int wave = tid >> 6, lane = tid & 63;
    const int l16 = lane & 15, qd = lane >> 4;
    const int m0 = blockIdx.y * 128, n0 = blockIdx.x * 128;
    const int mh = (wave >> 1) * 64, nh = (wave & 1) * 64;

    const int lrow = lane >> 3;
    const int cgw  = (lane & 7) ^ lrow;            // DMA global col-group swizzle
    const int cg0  = (qd ^ (l16 & 7)) * 8;         // frag col offset, ks=0 (elems)
    const int cg1  = ((4 | qd) ^ (l16 & 7)) * 8;   // ks=1

    floatx4 acc[4][4];
    #pragma unroll
    for (int mi = 0; mi < 4; mi++)
        #pragma unroll
        for (int ni = 0; ni < 4; ni++)
            acc[mi][ni] = (floatx4){0.f, 0.f, 0.f, 0.f};

    size_t gA[4], gB[4];
    unsigned short *lA[4], *lB[4];
    #pragma unroll
    for (int j = 0; j < 4; j++) {
        const int rb = wave * 32 + j * 8;
        gA[j] = (size_t)(m0 + rb + lrow) * DM + cgw * 8;
        gB[j] = (size_t)(n0 + rb + lrow) * DM + cgw * 8;
        lA[j] = &At[rb * 64];
        lB[j] = &Bt[rb * 64];
    }

    for (int k0 = 0; k0 < DM; k0 += 64) {
        __syncthreads();
        #pragma unroll
        for (int j = 0; j < 4; j++) {
            dma16(xb + gA[j] + k0, lA[j]);
            dma16(wt + gB[j] + k0, lB[j]);
        }
        __syncthreads();
        #pragma unroll
        for (int ks = 0; ks < 2; ks++) {
            const int cg = ks ? cg1 : cg0;
            shortx8 af[4], bfr[4];
            #pragma unroll
            for (int i = 0; i < 4; i++) {
                af[i]  = *(const shortx8*)&At[(mh + i * 16 + l16) * 64 + cg];
                bfr[i] = *(const shortx8*)&Bt[(nh + i * 16 + l16) * 64 + cg];
            }
            #pragma unroll
            for (int mi = 0; mi < 4; mi++)
                #pragma unroll
                for (int ni = 0; ni < 4; ni++)
                    acc[mi][ni] = __builtin_amdgcn_mfma_f32_16x16x32_bf16(
                        af[mi], bfr[ni], acc[mi][ni], 0, 0, 0);
        }
    }

    int ncol, H; unsigned short* dst; float sc; bool vtrans;
    if (n0 < 2048)      { ncol = n0;        dst = Qws; H = NQH;  sc = 0.125f * 1.44269504f; vtrans = false; }
    else if (n0 < 2560) { ncol = n0 - 2048; dst = Kws; H = NKVH; sc = 1.0f; vtrans = false; }
    else                { ncol = n0 - 2560; dst = Vws; H = NKVH; sc = 1.0f; vtrans = true;  }

    // C/D layout: col=lane&15, row=(lane>>4)*4+reg
    #pragma unroll
    for (int mi = 0; mi < 4; mi++)
        #pragma unroll
        for (int ni = 0; ni < 4; ni++)
            #pragma unroll
            for (int r = 0; r < 4; r++) {
                int m  = m0 + mh + mi * 16 + qd * 4 + r;
                int nc = ncol + nh + ni * 16 + l16;
                int b  = m >> 11, t = m & (T_SEQ - 1);
                int hh = nc >> 6, d = nc & 63;
                float v = acc[mi][ni][r] * sc;
                size_t idx = vtrans
                    ? ((((size_t)b * H + hh) * HD + d) << 11) + t
                    : ((((size_t)b * H + hh) * T_SEQ + t) << 6) + d;
                dst[idx] = f2bf(v);
            }
}

// ---------------------------------------------------------------------------
// Causal GQA flash attention, MFMA, K/V shared across the head group.
// Block = (qt, kv-head, b), 4 waves; wave w handles q-head kh*4+w, 64 q-rows.
// Q frags in registers; K [j][d] and V^T [d][j] staged via global_load_lds
// into XOR-swizzled unpadded LDS. Softmax base-2, fixed max (scores O(1)).
// P spill: truncated bf16, pair-packed b32 half-exec writes, padded buffer.
// ---------------------------------------------------------------------------
__global__ __launch_bounds__(256) void attn_fwd(
    const unsigned short* __restrict__ Qws,
    const unsigned short* __restrict__ Kws,
    const unsigned short* __restrict__ Vtws,
    float* __restrict__ out)
{
    __shared__ __align__(16) unsigned short Ks[64 * 64];
    __shared__ __align__(16) unsigned short Vt[64 * 64];
    __shared__ __align__(16) unsigned short Ps[4][64][72];

    const int tid = threadIdx.x;
    const int wave = tid >> 6, lane = tid & 63;
    const int l16 = lane & 15, qd = lane >> 4;
    const int qt = 31 - blockIdx.x;               // longest blocks first
    const int kh = blockIdx.y, b = blockIdx.z;
    const int h = kh * 4 + wave;
    const int q0 = qt * 64;

    const size_t qbase  = (((size_t)b * NQH + h) * T_SEQ + q0) * HD;
    const size_t kbase  = ((size_t)b * NKVH + kh) * (size_t)T_SEQ * HD;
    const size_t vtbase = ((size_t)b * NKVH + kh) * (size_t)HD * T_SEQ;

    // Q A-fragments in registers for the whole block
    shortx8 qfr[4][2];
    #pragma unroll
    for (int mt = 0; mt < 4; mt++)
        #pragma unroll
        for (int ks = 0; ks < 2; ks++)
            qfr[mt][ks] = *(const shortx8*)(Qws + qbase +
                (size_t)(mt * 16 + l16) * HD + ks * 32 + qd * 8);

    floatx4 oacc[4][4];
    #pragma unroll
    for (int mt = 0; mt < 4; mt++)
        #pragma unroll
        for (int dt = 0; dt < 4; dt++)
            oacc[mt][dt] = (floatx4){0.f, 0.f, 0.f, 0.f};
    float lsum[4][4];
    #pragma unroll
    for (int mt = 0; mt < 4; mt++)
        #pragma unroll
        for (int r = 0; r < 4; r++) lsum[mt][r] = 0.f;

    const int lrow = lane >> 3;
    const int cgw  = (lane & 7) ^ lrow;
    const int cg0  = (qd ^ (l16 & 7)) * 8;
    const int cg1  = ((4 | qd) ^ (l16 & 7)) * 8;

    for (int c = 0; c <= qt; c++) {
        const int j0 = c * 64;
        __syncthreads();
        #pragma unroll
        for (int j2 = 0; j2 < 2; j2++) {
            const int rb = wave * 16 + j2 * 8;
            dma16(Kws  + kbase  + (size_t)(j0 + rb + lrow) * HD + cgw * 8, &Ks[rb * 64]);
            dma16(Vtws + vtbase + (size_t)(rb + lrow) * T_SEQ + j0 + cgw * 8, &Vt[rb * 64]);
        }
        __syncthreads();

        const bool diag = (c == qt);
        // ---- S = Q K^T, P = 2^S, spill P (per-wave private) ----
        #pragma unroll
        for (int nt = 0; nt < 4; nt++) {
            const shortx8 kf0 = *(const shortx8*)&Ks[(nt * 16 + l16) * 64 + cg0];
            const shortx8 kf1 = *(const shortx8*)&Ks[(nt * 16 + l16) * 64 + cg1];
            const int jcol = j0 + nt * 16 + l16;
            #pragma unroll
            for (int mt = 0; mt < 4; mt++) {
                floatx4 s = (floatx4){0.f, 0.f, 0.f, 0.f};
                s = __builtin_amdgcn_mfma_f32_16x16x32_bf16(qfr[mt][0], kf0, s, 0, 0, 0);
                s = __builtin_amdgcn_mfma_f32_16x16x32_bf16(qfr[mt][1], kf1, s, 0, 0, 0);
                #pragma unroll
                for (int r = 0; r < 4; r++) {
                    float pe = exp2f(s[r]);
                    unsigned int pu = __builtin_bit_cast(unsigned int, pe) & 0xFFFF0000u;
                    if (diag && jcol > q0 + mt * 16 + qd * 4 + r) pu = 0u;
                    float pt = __builtin_bit_cast(float, pu);   // truncated bf16 value
                    lsum[mt][r] += pt;                           // consistent with MFMA P
                    float po = __shfl_xor(pt, 1, 64);
                    if (!(lane & 1)) {
                        unsigned int dw = (pu >> 16) |
                            (__builtin_bit_cast(unsigned int, po) & 0xFFFF0000u);
                        *(unsigned int*)&Ps[wave][mt * 16 + qd * 4 + r][nt * 16 + l16] = dw;
                    }
                }
            }
        }

        // ---- O += P V ----
        shortx8 pfr[4][2];
        #pragma unroll
        for (int mt = 0; mt < 4; mt++) {
            pfr[mt][0] = *(const shortx8*)&Ps[wave][mt * 16 + l16][qd * 8];
            pfr[mt][1] = *(const shortx8*)&Ps[wave][mt * 16 + l16][32 + qd * 8];
        }
        #pragma unroll
        for (int dt = 0; dt < 4; dt++) {
            const shortx8 vf0 = *(const shortx8*)&Vt[(dt * 16 + l16) * 64 + cg0];
            const shortx8 vf1 = *(const shortx8*)&Vt[(dt * 16 + l16) * 64 + cg1];
            #pragma unroll
            for (int mt = 0; mt < 4; mt++) {
                oacc[mt][dt] = __builtin_amdgcn_mfma_f32_16x16x32_bf16(pfr[mt][0], vf0, oacc[mt][dt], 0, 0, 0);
                oacc[mt][dt] = __builtin_amdgcn_mfma_f32_16x16x32_bf16(pfr[mt][1], vf1, oacc[mt][dt], 0, 0, 0);
            }
        }
    }

    // ---- row-sum reduction across the 16-lane column group ----
    float inv[4][4];
    #pragma unroll
    for (int mt = 0; mt < 4; mt++)
        #pragma unroll
        for (int r = 0; r < 4; r++) {
            float s = lsum[mt][r];
            s += __shfl_xor(s, 1, 64);
            s += __shfl_xor(s, 2, 64);
            s += __shfl_xor(s, 4, 64);
            s += __shfl_xor(s, 8, 64);
            inv[mt][r] = 1.f / s;
        }

    // ---- epilogue: O C-layout (row=qd*4+r, col=l16) ----
    #pragma unroll
    for (int mt = 0; mt < 4; mt++)
        #pragma unroll
        for (int dt = 0; dt < 4; dt++)
            #pragma unroll
            for (int r = 0; r < 4; r++) {
                const int t = q0 + mt * 16 + qd * 4 + r;
                out[((size_t)b * T_SEQ + t) * (NQH * HD) + h * HD + dt * 16 + l16] =
                    oacc[mt][dt][r] * inv[mt][r];
            }
}

extern "C" void kernel_launch(void* const* d_in, const int* in_sizes, int n_in,
                              void* d_out, int out_size, void* d_ws, size_t ws_size,
                              hipStream_t stream) {
    const float* x  = (const float*)d_in[0];
    const float* Wq = (const float*)d_in[1];
    const float* Wk = (const float*)d_in[2];
    const float* Wv = (const float*)d_in[3];
    float* out = (float*)d_out;

    // xb scratch lives in d_out (16.8 MB of 33.5 MB) — dead before attn writes.
    unsigned short* xb  = (unsigned short*)d_out;
    unsigned short* wt  = (unsigned short*)d_ws;                  // 12.6 MB
    unsigned short* Qws = wt  + (size_t)NTOT * DM;                // 16.8 MB
    unsigned short* Kws = Qws + (size_t)2 * NQH * T_SEQ * HD;     // 4.2 MB
    unsigned short* Vws = Kws + (size_t)2 * NKVH * T_SEQ * HD;    // 4.2 MB

    cvt_x   <<<4096, 256, 0, stream>>>(x, xb);
    cvt_wt  <<<dim3(32, 48), 256, 0, stream>>>(Wq, Wk, Wv, wt);
    qkv_gemm<<<dim3(24, 32), 256, 0, stream>>>(xb, wt, Qws, Kws, Vws);
    attn_fwd<<<dim3(32, NKVH, 2), 256, 0, stream>>>(Qws, Kws, Vws, out);
}

// Round 4
// 295.878 us; speedup vs baseline: 1.3996x; 1.3996x over previous
//
#include <hip/hip_runtime.h>

typedef float floatx4 __attribute__((ext_vector_type(4)));
typedef short shortx8 __attribute__((ext_vector_type(8)));

#define T_SEQ 2048
#define NQH   32
#define NKVH  8
#define HD    64
#define DM    2048
#define NTOT  3072

__device__ __forceinline__ unsigned short f2bf(float f) {
    unsigned int u = __builtin_bit_cast(unsigned int, f);
    u += 0x7FFFu + ((u >> 16) & 1u);          // RNE
    return (unsigned short)(u >> 16);
}
__device__ __forceinline__ unsigned int pk2bf(float a, float b) {
    return (unsigned int)f2bf(a) | ((unsigned int)f2bf(b) << 16);
}

// async global->LDS, 16B per lane; LDS dest = wave-uniform base + lane*16
__device__ __forceinline__ void dma16(const unsigned short* g, unsigned short* l) {
    __builtin_amdgcn_global_load_lds(
        (const __attribute__((address_space(1))) unsigned int*)g,
        (__attribute__((address_space(3))) unsigned int*)l,
        16, 0, 0);
}

// ---------------------------------------------------------------------------
// x fp32 -> bf16 (into d_out scratch). 4096 blocks x 256 thr x 8 elems.
// ---------------------------------------------------------------------------
__global__ __launch_bounds__(256) void cvt_x(const float* __restrict__ x,
                                             unsigned short* __restrict__ xb) {
    size_t i = ((size_t)blockIdx.x * 256 + threadIdx.x) * 8;
    float4 a = *(const float4*)(x + i);
    float4 b = *(const float4*)(x + i + 4);
    uint4 o;
    o.x = pk2bf(a.x, a.y); o.y = pk2bf(a.z, a.w);
    o.z = pk2bf(b.x, b.y); o.w = pk2bf(b.z, b.w);
    *(uint4*)(xb + i) = o;
}

// ---------------------------------------------------------------------------
// W [k][n] fp32 -> Wt [n][k] bf16 (rows 0-2047 Wq^T, 2048-2559 Wk^T, rest Wv^T)
// ---------------------------------------------------------------------------
__global__ __launch_bounds__(256) void cvt_wt(const float* __restrict__ Wq,
                                              const float* __restrict__ Wk,
                                              const float* __restrict__ Wv,
                                              unsigned short* __restrict__ wt) {
    __shared__ __align__(16) unsigned short Ts[64][72];
    const int k0 = blockIdx.x * 64, n0g = blockIdx.y * 64;
    const float* W; int ldW, col0;
    if (n0g < 2048)      { W = Wq; ldW = 2048; col0 = n0g; }
    else if (n0g < 2560) { W = Wk; ldW = 512;  col0 = n0g - 2048; }
    else                 { W = Wv; ldW = 512;  col0 = n0g - 2560; }
    const int t = threadIdx.x;
    {
        int r = t >> 2, c = (t & 3) * 16;
        const float* src = W + (size_t)(k0 + r) * ldW + col0 + c;
        float4 v0 = *(const float4*)(src);
        float4 v1 = *(const float4*)(src + 4);
        float4 v2 = *(const float4*)(src + 8);
        float4 v3 = *(const float4*)(src + 12);
        uint4 o0 = {pk2bf(v0.x, v0.y), pk2bf(v0.z, v0.w), pk2bf(v1.x, v1.y), pk2bf(v1.z, v1.w)};
        uint4 o1 = {pk2bf(v2.x, v2.y), pk2bf(v2.z, v2.w), pk2bf(v3.x, v3.y), pk2bf(v3.z, v3.w)};
        *(uint4*)&Ts[r][c]     = o0;
        *(uint4*)&Ts[r][c + 8] = o1;
    }
    __syncthreads();
    {
        int n = t >> 2, kc = (t & 3) * 16;
        unsigned int dw[8];
        #pragma unroll
        for (int i = 0; i < 8; i++)
            dw[i] = (unsigned int)Ts[kc + 2 * i][n] | ((unsigned int)Ts[kc + 2 * i + 1][n] << 16);
        uint4 o0 = {dw[0], dw[1], dw[2], dw[3]}, o1 = {dw[4], dw[5], dw[6], dw[7]};
        unsigned short* d = wt + (size_t)(n0g + n) * DM + k0 + kc;
        *(uint4*)d = o0; *(uint4*)(d + 8) = o1;
    }
}

// ---------------------------------------------------------------------------
// Fused QKV GEMM, all-bf16, double-buffered LDS + single barrier per k-step:
// the prefetch DMA for step k+1 is issued right after the barrier, landing
// during step-k compute, so the next barrier's vmcnt drain is cheap.
// 128x128 tile, BK=64, XOR-swizzled tiles, 4 waves, 4x4 of 16x16x32 MFMA.
// ---------------------------------------------------------------------------
__global__ __launch_bounds__(256) void qkv_gemm(
    const unsigned short* __restrict__ xb,   // [4096][2048]
    const unsigned short* __restrict__ wt,   // [3072][2048]
    unsigned short* __restrict__ Qws, unsigned short* __restrict__ Kws,
    unsigned short* __restrict__ Vws)
{
    __shared__ __align__(16) unsigned short At[2][128 * 64];
    __shared__ __align__(16) unsigned short Bt[2][128 * 64];

    const int tid = threadIdx.x;
    const int wave = tid >> 6, lane = tid & 63;
    const int l16 = lane & 15, qd = lane >> 4;
    const int m0 = blockIdx.y * 128, n0 = blockIdx.x * 128;
    const int mh = (wave >> 1) * 64, nh = (wave & 1) * 64;

    const int lrow = lane >> 3;
    const int cgw  = (lane & 7) ^ lrow;            // DMA global col-group swizzle
    const int cg0  = (qd ^ (l16 & 7)) * 8;         // frag col offset, ks=0
    const int cg1  = ((4 | qd) ^ (l16 & 7)) * 8;   // ks=1

    floatx4 acc[4][4];
    #pragma unroll
    for (int mi = 0; mi < 4; mi++)
        #pragma unroll
        for (int ni = 0; ni < 4; ni++)
            acc[mi][ni] = (floatx4){0.f, 0.f, 0.f, 0.f};

    size_t gA[4], gB[4];
    int lofs[4];
    #pragma unroll
    for (int j = 0; j < 4; j++) {
        const int rb = wave * 32 + j * 8;
        gA[j] = (size_t)(m0 + rb + lrow) * DM + cgw * 8;
        gB[j] = (size_t)(n0 + rb + lrow) * DM + cgw * 8;
        lofs[j] = rb * 64;
    }

    // prologue: stage k0=0 into buffer 0
    #pragma unroll
    for (int j = 0; j < 4; j++) {
        dma16(xb + gA[j], &At[0][lofs[j]]);
        dma16(wt + gB[j], &Bt[0][lofs[j]]);
    }

    for (int k0 = 0; k0 < DM; k0 += 64) {
        const int cur = (k0 >> 6) & 1;
        __syncthreads();                       // buf[cur] ready; buf[cur^1] free
        if (k0 + 64 < DM) {
            #pragma unroll
            for (int j = 0; j < 4; j++) {
                dma16(xb + gA[j] + k0 + 64, &At[cur ^ 1][lofs[j]]);
                dma16(wt + gB[j] + k0 + 64, &Bt[cur ^ 1][lofs[j]]);
            }
        }
        #pragma unroll
        for (int ks = 0; ks < 2; ks++) {
            const int cg = ks ? cg1 : cg0;
            shortx8 af[4], bfr[4];
            #pragma unroll
            for (int i = 0; i < 4; i++) {
                af[i]  = *(const shortx8*)&At[cur][(mh + i * 16 + l16) * 64 + cg];
                bfr[i] = *(const shortx8*)&Bt[cur][(nh + i * 16 + l16) * 64 + cg];
            }
            #pragma unroll
            for (int mi = 0; mi < 4; mi++)
                #pragma unroll
                for (int ni = 0; ni < 4; ni++)
                    acc[mi][ni] = __builtin_amdgcn_mfma_f32_16x16x32_bf16(
                        af[mi], bfr[ni], acc[mi][ni], 0, 0, 0);
        }
    }

    int ncol, H; unsigned short* dst; float sc; bool vtrans;
    if (n0 < 2048)      { ncol = n0;        dst = Qws; H = NQH;  sc = 0.125f * 1.44269504f; vtrans = false; }
    else if (n0 < 2560) { ncol = n0 - 2048; dst = Kws; H = NKVH; sc = 1.0f; vtrans = false; }
    else                { ncol = n0 - 2560; dst = Vws; H = NKVH; sc = 1.0f; vtrans = true;  }

    // C/D layout: col=lane&15, row=(lane>>4)*4+reg
    #pragma unroll
    for (int mi = 0; mi < 4; mi++)
        #pragma unroll
        for (int ni = 0; ni < 4; ni++)
            #pragma unroll
            for (int r = 0; r < 4; r++) {
                int m  = m0 + mh + mi * 16 + qd * 4 + r;
                int nc = ncol + nh + ni * 16 + l16;
                int b  = m >> 11, t = m & (T_SEQ - 1);
                int hh = nc >> 6, d = nc & 63;
                float v = acc[mi][ni][r] * sc;
                size_t idx = vtrans
                    ? ((((size_t)b * H + hh) * HD + d) << 11) + t
                    : ((((size_t)b * H + hh) * T_SEQ + t) << 6) + d;
                dst[idx] = f2bf(v);
            }
}

// ---------------------------------------------------------------------------
// Causal GQA flash attention, MFMA, K/V shared across the head group.
// Block = (qt, kh, b), 4 waves; wave w = q-head kh*4+w, 64 q-rows.
// Double-buffered K/V chunks, ONE barrier per chunk (prefetch overlaps
// compute). P-spill via full-exec ds_write_b16 (no shfl). K/P frags cached
// in registers (2 blocks/CU, 2 waves/SIMD). qt mapping pairs z=0 (31-x)
// with z=1 (x) so co-resident blocks sum to 33 chunks (uniform makespan).
// ---------------------------------------------------------------------------
__global__ __launch_bounds__(256) void attn_fwd(
    const unsigned short* __restrict__ Qws,
    const unsigned short* __restrict__ Kws,
    const unsigned short* __restrict__ Vtws,
    float* __restrict__ out)
{
    __shared__ __align__(16) unsigned short Ks[2][64 * 64];
    __shared__ __align__(16) unsigned short Vt[2][64 * 64];
    __shared__ __align__(16) unsigned short Ps[4][64][72];

    const int tid = threadIdx.x;
    const int wave = tid >> 6, lane = tid & 63;
    const int l16 = lane & 15, qd = lane >> 4;
    const int b = blockIdx.z;
    const int qt = b ? blockIdx.x : (31 - blockIdx.x);   // CU-pair balance
    const int kh = blockIdx.y;
    const int h = kh * 4 + wave;
    const int q0 = qt * 64;

    const size_t qbase  = (((size_t)b * NQH + h) * T_SEQ + q0) * HD;
    const size_t kbase  = ((size_t)b * NKVH + kh) * (size_t)T_SEQ * HD;
    const size_t vtbase = ((size_t)b * NKVH + kh) * (size_t)HD * T_SEQ;

    // Q A-fragments in registers for the whole block
    shortx8 qfr[4][2];
    #pragma unroll
    for (int mt = 0; mt < 4; mt++)
        #pragma unroll
        for (int ks = 0; ks < 2; ks++)
            qfr[mt][ks] = *(const shortx8*)(Qws + qbase +
                (size_t)(mt * 16 + l16) * HD + ks * 32 + qd * 8);

    floatx4 oacc[4][4];
    #pragma unroll
    for (int mt = 0; mt < 4; mt++)
        #pragma unroll
        for (int dt = 0; dt < 4; dt++)
            oacc[mt][dt] = (floatx4){0.f, 0.f, 0.f, 0.f};
    float lsum[4][4];
    #pragma unroll
    for (int mt = 0; mt < 4; mt++)
        #pragma unroll
        for (int r = 0; r < 4; r++) lsum[mt][r] = 0.f;

    const int lrow = lane >> 3;
    const int cgw  = (lane & 7) ^ lrow;
    const int cg0  = (qd ^ (l16 & 7)) * 8;
    const int cg1  = ((4 | qd) ^ (l16 & 7)) * 8;

    // prologue: stage chunk 0 into buffer 0
    #pragma unroll
    for (int j2 = 0; j2 < 2; j2++) {
        const int rb = wave * 16 + j2 * 8;
        dma16(Kws  + kbase  + (size_t)(rb + lrow) * HD + cgw * 8, &Ks[0][rb * 64]);
        dma16(Vtws + vtbase + (size_t)(rb + lrow) * T_SEQ + cgw * 8, &Vt[0][rb * 64]);
    }

    for (int c = 0; c <= qt; c++) {
        const int cur = c & 1;
        const int j0 = c * 64;
        __syncthreads();          // chunk c landed; buffer cur^1 free
        if (c < qt) {
            const int j0n = j0 + 64;
            #pragma unroll
            for (int j2 = 0; j2 < 2; j2++) {
                const int rb = wave * 16 + j2 * 8;
                dma16(Kws  + kbase  + (size_t)(j0n + rb + lrow) * HD + cgw * 8,
                      &Ks[cur ^ 1][rb * 64]);
                dma16(Vtws + vtbase + (size_t)(rb + lrow) * T_SEQ + j0n + cgw * 8,
                      &Vt[cur ^ 1][rb * 64]);
            }
        }

        // ---- K fragments for this chunk (cached in regs) ----
        shortx8 kf[4][2];
        #pragma unroll
        for (int nt = 0; nt < 4; nt++) {
            kf[nt][0] = *(const shortx8*)&Ks[cur][(nt * 16 + l16) * 64 + cg0];
            kf[nt][1] = *(const shortx8*)&Ks[cur][(nt * 16 + l16) * 64 + cg1];
        }

        const bool diag = (c == qt);
        // ---- S = Q K^T, P = 2^S, spill P (b16, full exec) ----
        #pragma unroll
        for (int nt = 0; nt < 4; nt++) {
            const int jcol = j0 + nt * 16 + l16;
            #pragma unroll
            for (int mt = 0; mt < 4; mt++) {
                floatx4 s = (floatx4){0.f, 0.f, 0.f, 0.f};
                s = __builtin_amdgcn_mfma_f32_16x16x32_bf16(qfr[mt][0], kf[nt][0], s, 0, 0, 0);
                s = __builtin_amdgcn_mfma_f32_16x16x32_bf16(qfr[mt][1], kf[nt][1], s, 0, 0, 0);
                #pragma unroll
                for (int r = 0; r < 4; r++) {
                    float pe = exp2f(s[r]);
                    unsigned int pu = __builtin_bit_cast(unsigned int, pe) & 0xFFFF0000u;
                    if (diag && jcol > q0 + mt * 16 + qd * 4 + r) pu = 0u;
                    lsum[mt][r] += __builtin_bit_cast(float, pu);  // consistent w/ MFMA P
                    Ps[wave][mt * 16 + qd * 4 + r][nt * 16 + l16] =
                        (unsigned short)(pu >> 16);
                }
            }
        }

        // ---- P fragments (same-wave LDS round trip) ----
        shortx8 pfr[4][2];
        #pragma unroll
        for (int mt = 0; mt < 4; mt++) {
            pfr[mt][0] = *(const shortx8*)&Ps[wave][mt * 16 + l16][qd * 8];
            pfr[mt][1] = *(const shortx8*)&Ps[wave][mt * 16 + l16][32 + qd * 8];
        }

        // ---- O += P V ----
        #pragma unroll
        for (int dt = 0; dt < 4; dt++) {
            const shortx8 vf0 = *(const shortx8*)&Vt[cur][(dt * 16 + l16) * 64 + cg0];
            const shortx8 vf1 = *(const shortx8*)&Vt[cur][(dt * 16 + l16) * 64 + cg1];
            #pragma unroll
            for (int mt = 0; mt < 4; mt++) {
                oacc[mt][dt] = __builtin_amdgcn_mfma_f32_16x16x32_bf16(pfr[mt][0], vf0, oacc[mt][dt], 0, 0, 0);
                oacc[mt][dt] = __builtin_amdgcn_mfma_f32_16x16x32_bf16(pfr[mt][1], vf1, oacc[mt][dt], 0, 0, 0);
            }
        }
    }

    // ---- row-sum reduction across the 16-lane column group ----
    float inv[4][4];
    #pragma unroll
    for (int mt = 0; mt < 4; mt++)
        #pragma unroll
        for (int r = 0; r < 4; r++) {
            float s = lsum[mt][r];
            s += __shfl_xor(s, 1, 64);
            s += __shfl_xor(s, 2, 64);
            s += __shfl_xor(s, 4, 64);
            s += __shfl_xor(s, 8, 64);
            inv[mt][r] = 1.f / s;
        }

    // ---- epilogue: O C-layout (row=qd*4+r, col=l16) ----
    #pragma unroll
    for (int mt = 0; mt < 4; mt++)
        #pragma unroll
        for (int dt = 0; dt < 4; dt++)
            #pragma unroll
            for (int r = 0; r < 4; r++) {
                const int t = q0 + mt * 16 + qd * 4 + r;
                out[((size_t)b * T_SEQ + t) * (NQH * HD) + h * HD + dt * 16 + l16] =
                    oacc[mt][dt][r] * inv[mt][r];
            }
}

extern "C" void kernel_launch(void* const* d_in, const int* in_sizes, int n_in,
                              void* d_out, int out_size, void* d_ws, size_t ws_size,
                              hipStream_t stream) {
    const float* x  = (const float*)d_in[0];
    const float* Wq = (const float*)d_in[1];
    const float* Wk = (const float*)d_in[2];
    const float* Wv = (const float*)d_in[3];
    float* out = (float*)d_out;

    // xb scratch lives in d_out (16.8 MB of 33.5 MB) — dead before attn writes.
    unsigned short* xb  = (unsigned short*)d_out;
    unsigned short* wt  = (unsigned short*)d_ws;                  // 12.6 MB
    unsigned short* Qws = wt  + (size_t)NTOT * DM;                // 16.8 MB
    unsigned short* Kws = Qws + (size_t)2 * NQH * T_SEQ * HD;     // 4.2 MB
    unsigned short* Vws = Kws + (size_t)2 * NKVH * T_SEQ * HD;    // 4.2 MB

    cvt_x   <<<4096, 256, 0, stream>>>(x, xb);
    cvt_wt  <<<dim3(32, 48), 256, 0, stream>>>(Wq, Wk, Wv, wt);
    qkv_gemm<<<dim3(24, 32), 256, 0, stream>>>(xb, wt, Qws, Kws, Vws);
    attn_fwd<<<dim3(32, NKVH, 2), 256, 0, stream>>>(Qws, Kws, Vws, out);
}

// Round 5
// 261.030 us; speedup vs baseline: 1.5865x; 1.1335x over previous
//
#include <hip/hip_runtime.h>

typedef float floatx4 __attribute__((ext_vector_type(4)));
typedef short shortx8 __attribute__((ext_vector_type(8)));

#define T_SEQ 2048
#define NQH   32
#define NKVH  8
#define HD    64
#define DM    2048
#define NTOT  3072

#if __has_builtin(__builtin_amdgcn_exp2f)
#define EXP2F(x) __builtin_amdgcn_exp2f(x)
#else
#define EXP2F(x) exp2f(x)
#endif

__device__ __forceinline__ unsigned short f2bf(float f) {
    unsigned int u = __builtin_bit_cast(unsigned int, f);
    u += 0x7FFFu + ((u >> 16) & 1u);          // RNE
    return (unsigned short)(u >> 16);
}
__device__ __forceinline__ unsigned int pk2bf(float a, float b) {
    return (unsigned int)f2bf(a) | ((unsigned int)f2bf(b) << 16);
}

// async global->LDS, 16B per lane; LDS dest = wave-uniform base + lane*16
__device__ __forceinline__ void dma16(const unsigned short* g, unsigned short* l) {
    __builtin_amdgcn_global_load_lds(
        (const __attribute__((address_space(1))) unsigned int*)g,
        (__attribute__((address_space(3))) unsigned int*)l,
        16, 0, 0);
}

// ---------------------------------------------------------------------------
// x fp32 -> bf16 (into d_out scratch). 4096 blocks x 256 thr x 8 elems.
// ---------------------------------------------------------------------------
__global__ __launch_bounds__(256) void cvt_x(const float* __restrict__ x,
                                             unsigned short* __restrict__ xb) {
    size_t i = ((size_t)blockIdx.x * 256 + threadIdx.x) * 8;
    float4 a = *(const float4*)(x + i);
    float4 b = *(const float4*)(x + i + 4);
    uint4 o;
    o.x = pk2bf(a.x, a.y); o.y = pk2bf(a.z, a.w);
    o.z = pk2bf(b.x, b.y); o.w = pk2bf(b.z, b.w);
    *(uint4*)(xb + i) = o;
}

// ---------------------------------------------------------------------------
// W [k][n] fp32 -> Wt [n][k] bf16 (rows 0-2047 Wq^T, 2048-2559 Wk^T, rest Wv^T)
// ---------------------------------------------------------------------------
__global__ __launch_bounds__(256) void cvt_wt(const float* __restrict__ Wq,
                                              const float* __restrict__ Wk,
                                              const float* __restrict__ Wv,
                                              unsigned short* __restrict__ wt) {
    __shared__ __align__(16) unsigned short Ts[64][72];
    const int k0 = blockIdx.x * 64, n0g = blockIdx.y * 64;
    const float* W; int ldW, col0;
    if (n0g < 2048)      { W = Wq; ldW = 2048; col0 = n0g; }
    else if (n0g < 2560) { W = Wk; ldW = 512;  col0 = n0g - 2048; }
    else                 { W = Wv; ldW = 512;  col0 = n0g - 2560; }
    const int t = threadIdx.x;
    {
        int r = t >> 2, c = (t & 3) * 16;
        const float* src = W + (size_t)(k0 + r) * ldW + col0 + c;
        float4 v0 = *(const float4*)(src);
        float4 v1 = *(const float4*)(src + 4);
        float4 v2 = *(const float4*)(src + 8);
        float4 v3 = *(const float4*)(src + 12);
        uint4 o0 = {pk2bf(v0.x, v0.y), pk2bf(v0.z, v0.w), pk2bf(v1.x, v1.y), pk2bf(v1.z, v1.w)};
        uint4 o1 = {pk2bf(v2.x, v2.y), pk2bf(v2.z, v2.w), pk2bf(v3.x, v3.y), pk2bf(v3.z, v3.w)};
        *(uint4*)&Ts[r][c]     = o0;
        *(uint4*)&Ts[r][c + 8] = o1;
    }
    __syncthreads();
    {
        int n = t >> 2, kc = (t & 3) * 16;
        unsigned int dw[8];
        #pragma unroll
        for (int i = 0; i < 8; i++)
            dw[i] = (unsigned int)Ts[kc + 2 * i][n] | ((unsigned int)Ts[kc + 2 * i + 1][n] << 16);
        uint4 o0 = {dw[0], dw[1], dw[2], dw[3]}, o1 = {dw[4], dw[5], dw[6], dw[7]};
        unsigned short* d = wt + (size_t)(n0g + n) * DM + k0 + kc;
        *(uint4*)d = o0; *(uint4*)(d + 8) = o1;
    }
}

// ---------------------------------------------------------------------------
// Fused QKV GEMM, all-bf16, double-buffered LDS, single barrier per k-step.
// XCD-grouped block swizzle: id&7 -> XCD (round-robin dispatch heuristic);
// each XCD works 4 m-tiles x 24 n-tiles, n cycled slowly -> A tiles (2 MB)
// L2-resident, B tile shared by 4 adjacent blocks. Cuts L3 traffic ~6x.
// ---------------------------------------------------------------------------
__global__ __launch_bounds__(256) void qkv_gemm(
    const unsigned short* __restrict__ xb,   // [4096][2048]
    const unsigned short* __restrict__ wt,   // [3072][2048]
    unsigned short* __restrict__ Qws, unsigned short* __restrict__ Kws,
    unsigned short* __restrict__ Vws)
{
    __shared__ __align__(16) unsigned short At[2][128 * 64];
    __shared__ __align__(16) unsigned short Bt[2][128 * 64];

    const int tid = threadIdx.x;
    const int wave = tid >> 6, lane = tid & 63;
    const int l16 = lane & 15, qd = lane >> 4;

    // XCD locality swizzle (dispatch linear id, x fastest)
    const int id  = blockIdx.y * 24 + blockIdx.x;       // 0..767
    const int xcd = id & 7, j = id >> 3;                // j 0..95
    const int m0 = (xcd * 4 + (j & 3)) * 128;           // 32 m-tiles
    const int n0 = (j >> 2) * 128;                      // 24 n-tiles

    const int mh = (wave >> 1) * 64, nh = (wave & 1) * 64;

    const int lrow = lane >> 3;
    const int cgw  = (lane & 7) ^ lrow;            // DMA global col-group swizzle
    const int cg0  = (qd ^ (l16 & 7)) * 8;         // frag col offset, ks=0
    const int cg1  = ((4 | qd) ^ (l16 & 7)) * 8;   // ks=1

    floatx4 acc[4][4];
    #pragma unroll
    for (int mi = 0; mi < 4; mi++)
        #pragma unroll
        for (int ni = 0; ni < 4; ni++)
            acc[mi][ni] = (floatx4){0.f, 0.f, 0.f, 0.f};

    size_t gA[4], gB[4];
    int lofs[4];
    #pragma unroll
    for (int jj = 0; jj < 4; jj++) {
        const int rb = wave * 32 + jj * 8;
        gA[jj] = (size_t)(m0 + rb + lrow) * DM + cgw * 8;
        gB[jj] = (size_t)(n0 + rb + lrow) * DM + cgw * 8;
        lofs[jj] = rb * 64;
    }

    // prologue: stage k0=0 into buffer 0
    #pragma unroll
    for (int jj = 0; jj < 4; jj++) {
        dma16(xb + gA[jj], &At[0][lofs[jj]]);
        dma16(wt + gB[jj], &Bt[0][lofs[jj]]);
    }

    for (int k0 = 0; k0 < DM; k0 += 64) {
        const int cur = (k0 >> 6) & 1;
        __syncthreads();                       // buf[cur] ready; buf[cur^1] free
        if (k0 + 64 < DM) {
            #pragma unroll
            for (int jj = 0; jj < 4; jj++) {
                dma16(xb + gA[jj] + k0 + 64, &At[cur ^ 1][lofs[jj]]);
                dma16(wt + gB[jj] + k0 + 64, &Bt[cur ^ 1][lofs[jj]]);
            }
        }
        #pragma unroll
        for (int ks = 0; ks < 2; ks++) {
            const int cg = ks ? cg1 : cg0;
            shortx8 af[4], bfr[4];
            #pragma unroll
            for (int i = 0; i < 4; i++) {
                af[i]  = *(const shortx8*)&At[cur][(mh + i * 16 + l16) * 64 + cg];
                bfr[i] = *(const shortx8*)&Bt[cur][(nh + i * 16 + l16) * 64 + cg];
            }
            #pragma unroll
            for (int mi = 0; mi < 4; mi++)
                #pragma unroll
                for (int ni = 0; ni < 4; ni++)
                    acc[mi][ni] = __builtin_amdgcn_mfma_f32_16x16x32_bf16(
                        af[mi], bfr[ni], acc[mi][ni], 0, 0, 0);
        }
    }

    int ncol, H; unsigned short* dst; float sc; bool vtrans;
    if (n0 < 2048)      { ncol = n0;        dst = Qws; H = NQH;  sc = 0.125f * 1.44269504f; vtrans = false; }
    else if (n0 < 2560) { ncol = n0 - 2048; dst = Kws; H = NKVH; sc = 1.0f; vtrans = false; }
    else                { ncol = n0 - 2560; dst = Vws; H = NKVH; sc = 1.0f; vtrans = true;  }

    // C/D layout: col=lane&15, row=(lane>>4)*4+reg
    #pragma unroll
    for (int mi = 0; mi < 4; mi++)
        #pragma unroll
        for (int ni = 0; ni < 4; ni++)
            #pragma unroll
            for (int r = 0; r < 4; r++) {
                int m  = m0 + mh + mi * 16 + qd * 4 + r;
                int nc = ncol + nh + ni * 16 + l16;
                int b  = m >> 11, t = m & (T_SEQ - 1);
                int hh = nc >> 6, d = nc & 63;
                float v = acc[mi][ni][r] * sc;
                size_t idx = vtrans
                    ? ((((size_t)b * H + hh) * HD + d) << 11) + t
                    : ((((size_t)b * H + hh) * T_SEQ + t) << 6) + d;
                dst[idx] = f2bf(v);
            }
}

// ---------------------------------------------------------------------------
// Causal GQA flash attention, MFMA, K/V shared across the head group.
// Block = (qt, kh, b), 4 waves; wave w = q-head kh*4+w, 64 q-rows.
// Double-buffered K/V chunks, one barrier per chunk. Per-chunk work split
// into two 32-key windows (kp): QK (K=64) -> exp2 (native v_exp_f32) ->
// P-spill to a 64x32 window buffer -> PV as single K=32 MFMAs.
// LDS 51.2 KB -> 3 blocks/CU. Diag masking hoisted to a uniform branch.
// ---------------------------------------------------------------------------
__global__ __launch_bounds__(256, 3) void attn_fwd(
    const unsigned short* __restrict__ Qws,
    const unsigned short* __restrict__ Kws,
    const unsigned short* __restrict__ Vtws,
    float* __restrict__ out)
{
    __shared__ __align__(16) unsigned short Ks[2][64 * 64];
    __shared__ __align__(16) unsigned short Vt[2][64 * 64];
    __shared__ __align__(16) unsigned short Ps[4][64][36];   // 32-key window, pad 4

    const int tid = threadIdx.x;
    const int wave = tid >> 6, lane = tid & 63;
    const int l16 = lane & 15, qd = lane >> 4;
    const int b = blockIdx.z;
    const int qt = 31 - blockIdx.x;               // LPT: longest blocks first
    const int kh = blockIdx.y;
    const int h = kh * 4 + wave;
    const int q0 = qt * 64;

    const size_t qbase  = (((size_t)b * NQH + h) * T_SEQ + q0) * HD;
    const size_t kbase  = ((size_t)b * NKVH + kh) * (size_t)T_SEQ * HD;
    const size_t vtbase = ((size_t)b * NKVH + kh) * (size_t)HD * T_SEQ;

    // Q A-fragments in registers for the whole block
    shortx8 qfr[4][2];
    #pragma unroll
    for (int mt = 0; mt < 4; mt++)
        #pragma unroll
        for (int ks = 0; ks < 2; ks++)
            qfr[mt][ks] = *(const shortx8*)(Qws + qbase +
                (size_t)(mt * 16 + l16) * HD + ks * 32 + qd * 8);

    floatx4 oacc[4][4];
    #pragma unroll
    for (int mt = 0; mt < 4; mt++)
        #pragma unroll
        for (int dt = 0; dt < 4; dt++)
            oacc[mt][dt] = (floatx4){0.f, 0.f, 0.f, 0.f};
    float lsum[4][4];
    #pragma unroll
    for (int mt = 0; mt < 4; mt++)
        #pragma unroll
        for (int r = 0; r < 4; r++) lsum[mt][r] = 0.f;

    const int lrow = lane >> 3;
    const int cgw  = (lane & 7) ^ lrow;
    const int xr   = l16 & 7;          // XOR key for this lane's LDS rows

    // prologue: stage chunk 0 into buffer 0
    #pragma unroll
    for (int j2 = 0; j2 < 2; j2++) {
        const int rb = wave * 16 + j2 * 8;
        dma16(Kws  + kbase  + (size_t)(rb + lrow) * HD + cgw * 8, &Ks[0][rb * 64]);
        dma16(Vtws + vtbase + (size_t)(rb + lrow) * T_SEQ + cgw * 8, &Vt[0][rb * 64]);
    }

    for (int c = 0; c <= qt; c++) {
        const int cur = c & 1;
        const int j0 = c * 64;
        __syncthreads();          // chunk c landed; buffer cur^1 free
        if (c < qt) {
            const int j0n = j0 + 64;
            #pragma unroll
            for (int j2 = 0; j2 < 2; j2++) {
                const int rb = wave * 16 + j2 * 8;
                dma16(Kws  + kbase  + (size_t)(j0n + rb + lrow) * HD + cgw * 8,
                      &Ks[cur ^ 1][rb * 64]);
                dma16(Vtws + vtbase + (size_t)(rb + lrow) * T_SEQ + j0n + cgw * 8,
                      &Vt[cur ^ 1][rb * 64]);
            }
        }

        const bool diag = (c == qt);

        #pragma unroll
        for (int kp = 0; kp < 2; kp++) {
            // ---- K fragments for this 32-key window ----
            shortx8 kf[2][2];
            #pragma unroll
            for (int ntl = 0; ntl < 2; ntl++) {
                const int krow = ((kp * 2 + ntl) * 16 + l16) * 64;
                kf[ntl][0] = *(const shortx8*)&Ks[cur][krow + ((qd ^ xr) * 8)];
                kf[ntl][1] = *(const shortx8*)&Ks[cur][krow + (((4 | qd) ^ xr) * 8)];
            }

            // ---- S = Q K^T, P = 2^S, spill to window buffer ----
            #pragma unroll
            for (int mt = 0; mt < 4; mt++) {
                floatx4 s[2];
                #pragma unroll
                for (int ntl = 0; ntl < 2; ntl++) {
                    s[ntl] = (floatx4){0.f, 0.f, 0.f, 0.f};
                    s[ntl] = __builtin_amdgcn_mfma_f32_16x16x32_bf16(qfr[mt][0], kf[ntl][0], s[ntl], 0, 0, 0);
                    s[ntl] = __builtin_amdgcn_mfma_f32_16x16x32_bf16(qfr[mt][1], kf[ntl][1], s[ntl], 0, 0, 0);
                }
                if (diag) {
                    #pragma unroll
                    for (int ntl = 0; ntl < 2; ntl++) {
                        const int jrel = kp * 32 + ntl * 16 + l16;   // key - q0
                        #pragma unroll
                        for (int r = 0; r < 4; r++) {
                            const int qrel = mt * 16 + qd * 4 + r;
                            float pe = EXP2F(s[ntl][r]);
                            unsigned int pu = __builtin_bit_cast(unsigned int, pe);
                            if (jrel > qrel) { pe = 0.f; pu = 0u; }
                            lsum[mt][r] += pe;
                            Ps[wave][qrel][ntl * 16 + l16] = (unsigned short)(pu >> 16);
                        }
                    }
                } else {
                    #pragma unroll
                    for (int ntl = 0; ntl < 2; ntl++) {
                        #pragma unroll
                        for (int r = 0; r < 4; r++) {
                            float pe = EXP2F(s[ntl][r]);
                            lsum[mt][r] += pe;
                            Ps[wave][mt * 16 + qd * 4 + r][ntl * 16 + l16] =
                                (unsigned short)(__builtin_bit_cast(unsigned int, pe) >> 16);
                        }
                    }
                }
            }

            // ---- P fragments (same-wave LDS round trip) + V^T fragments ----
            shortx8 pfr[4];
            #pragma unroll
            for (int mt = 0; mt < 4; mt++)
                pfr[mt] = *(const shortx8*)&Ps[wave][mt * 16 + l16][qd * 8];

            #pragma unroll
            for (int dt = 0; dt < 4; dt++) {
                const shortx8 vf = *(const shortx8*)
                    &Vt[cur][(dt * 16 + l16) * 64 + (((kp * 4 + qd) ^ xr) * 8)];
                #pragma unroll
                for (int mt = 0; mt < 4; mt++)
                    oacc[mt][dt] = __builtin_amdgcn_mfma_f32_16x16x32_bf16(
                        pfr[mt], vf, oacc[mt][dt], 0, 0, 0);
            }
        }
    }

    // ---- row-sum reduction across the 16-lane column group ----
    float inv[4][4];
    #pragma unroll
    for (int mt = 0; mt < 4; mt++)
        #pragma unroll
        for (int r = 0; r < 4; r++) {
            float s = lsum[mt][r];
            s += __shfl_xor(s, 1, 64);
            s += __shfl_xor(s, 2, 64);
            s += __shfl_xor(s, 4, 64);
            s += __shfl_xor(s, 8, 64);
            inv[mt][r] = 1.f / s;
        }

    // ---- epilogue: O C-layout (row=qd*4+r, col=l16) ----
    #pragma unroll
    for (int mt = 0; mt < 4; mt++)
        #pragma unroll
        for (int dt = 0; dt < 4; dt++)
            #pragma unroll
            for (int r = 0; r < 4; r++) {
                const int t = q0 + mt * 16 + qd * 4 + r;
                out[((size_t)b * T_SEQ + t) * (NQH * HD) + h * HD + dt * 16 + l16] =
                    oacc[mt][dt][r] * inv[mt][r];
            }
}

extern "C" void kernel_launch(void* const* d_in, const int* in_sizes, int n_in,
                              void* d_out, int out_size, void* d_ws, size_t ws_size,
                              hipStream_t stream) {
    const float* x  = (const float*)d_in[0];
    const float* Wq = (const float*)d_in[1];
    const float* Wk = (const float*)d_in[2];
    const float* Wv = (const float*)d_in[3];
    float* out = (float*)d_out;

    // xb scratch lives in d_out (16.8 MB of 33.5 MB) — dead before attn writes.
    unsigned short* xb  = (unsigned short*)d_out;
    unsigned short* wt  = (unsigned short*)d_ws;                  // 12.6 MB
    unsigned short* Qws = wt  + (size_t)NTOT * DM;                // 16.8 MB
    unsigned short* Kws = Qws + (size_t)2 * NQH * T_SEQ * HD;     // 4.2 MB
    unsigned short* Vws = Kws + (size_t)2 * NKVH * T_SEQ * HD;    // 4.2 MB

    cvt_x   <<<4096, 256, 0, stream>>>(x, xb);
    cvt_wt  <<<dim3(32, 48), 256, 0, stream>>>(Wq, Wk, Wv, wt);
    qkv_gemm<<<dim3(24, 32), 256, 0, stream>>>(xb, wt, Qws, Kws, Vws);
    attn_fwd<<<dim3(32, NKVH, 2), 256, 0, stream>>>(Qws, Kws, Vws, out);
}

// Round 6
// 242.123 us; speedup vs baseline: 1.7103x; 1.0781x over previous
//
#include <hip/hip_runtime.h>

typedef float floatx4 __attribute__((ext_vector_type(4)));
typedef short shortx8 __attribute__((ext_vector_type(8)));

#define T_SEQ 2048
#define NQH   32
#define NKVH  8
#define HD    64
#define DM    2048
#define NTOT  3072

#if __has_builtin(__builtin_amdgcn_exp2f)
#define EXP2F(x) __builtin_amdgcn_exp2f(x)
#else
#define EXP2F(x) exp2f(x)
#endif

__device__ __forceinline__ unsigned short f2bf(float f) {
    unsigned int u = __builtin_bit_cast(unsigned int, f);
    u += 0x7FFFu + ((u >> 16) & 1u);          // RNE
    return (unsigned short)(u >> 16);
}
__device__ __forceinline__ unsigned int pk2bf(float a, float b) {
    return (unsigned int)f2bf(a) | ((unsigned int)f2bf(b) << 16);
}

// async global->LDS, 16B per lane; LDS dest = wave-uniform base + lane*16
__device__ __forceinline__ void dma16(const unsigned short* g, unsigned short* l) {
    __builtin_amdgcn_global_load_lds(
        (const __attribute__((address_space(1))) unsigned int*)g,
        (__attribute__((address_space(3))) unsigned int*)l,
        16, 0, 0);
}

// ---------------------------------------------------------------------------
// Fused conversion: blocks [0,4096) convert x fp32->bf16 (into d_out scratch);
// blocks [4096, 4096+1536) transpose-convert W -> Wt [n][k] bf16.
// ---------------------------------------------------------------------------
__global__ __launch_bounds__(256) void cvt_fused(
    const float* __restrict__ x, const float* __restrict__ Wq,
    const float* __restrict__ Wk, const float* __restrict__ Wv,
    unsigned short* __restrict__ xb, unsigned short* __restrict__ wt)
{
    __shared__ __align__(16) unsigned short Ts[64][72];
    const int id = blockIdx.x;
    const int t = threadIdx.x;
    if (id < 4096) {
        size_t i = ((size_t)id * 256 + t) * 8;
        float4 a = *(const float4*)(x + i);
        float4 b = *(const float4*)(x + i + 4);
        uint4 o;
        o.x = pk2bf(a.x, a.y); o.y = pk2bf(a.z, a.w);
        o.z = pk2bf(b.x, b.y); o.w = pk2bf(b.z, b.w);
        *(uint4*)(xb + i) = o;
        return;
    }
    const int id2 = id - 4096;
    const int k0 = (id2 & 31) * 64, n0g = (id2 >> 5) * 64;
    const float* W; int ldW, col0;
    if (n0g < 2048)      { W = Wq; ldW = 2048; col0 = n0g; }
    else if (n0g < 2560) { W = Wk; ldW = 512;  col0 = n0g - 2048; }
    else                 { W = Wv; ldW = 512;  col0 = n0g - 2560; }
    {
        int r = t >> 2, c = (t & 3) * 16;
        const float* src = W + (size_t)(k0 + r) * ldW + col0 + c;
        float4 v0 = *(const float4*)(src);
        float4 v1 = *(const float4*)(src + 4);
        float4 v2 = *(const float4*)(src + 8);
        float4 v3 = *(const float4*)(src + 12);
        uint4 o0 = {pk2bf(v0.x, v0.y), pk2bf(v0.z, v0.w), pk2bf(v1.x, v1.y), pk2bf(v1.z, v1.w)};
        uint4 o1 = {pk2bf(v2.x, v2.y), pk2bf(v2.z, v2.w), pk2bf(v3.x, v3.y), pk2bf(v3.z, v3.w)};
        *(uint4*)&Ts[r][c]     = o0;
        *(uint4*)&Ts[r][c + 8] = o1;
    }
    __syncthreads();
    {
        int n = t >> 2, kc = (t & 3) * 16;
        unsigned int dw[8];
        #pragma unroll
        for (int i = 0; i < 8; i++)
            dw[i] = (unsigned int)Ts[kc + 2 * i][n] | ((unsigned int)Ts[kc + 2 * i + 1][n] << 16);
        uint4 o0 = {dw[0], dw[1], dw[2], dw[3]}, o1 = {dw[4], dw[5], dw[6], dw[7]};
        unsigned short* d = wt + (size_t)(n0g + n) * DM + k0 + kc;
        *(uint4*)d = o0; *(uint4*)(d + 8) = o1;
    }
}

// ---------------------------------------------------------------------------
// Fused QKV GEMM, all-bf16, double-buffered LDS, single barrier per k-step.
// XCD-grouped block swizzle for L2 locality.
// ---------------------------------------------------------------------------
__global__ __launch_bounds__(256) void qkv_gemm(
    const unsigned short* __restrict__ xb,   // [4096][2048]
    const unsigned short* __restrict__ wt,   // [3072][2048]
    unsigned short* __restrict__ Qws, unsigned short* __restrict__ Kws,
    unsigned short* __restrict__ Vws)
{
    __shared__ __align__(16) unsigned short At[2][128 * 64];
    __shared__ __align__(16) unsigned short Bt[2][128 * 64];

    const int tid = threadIdx.x;
    const int wave = tid >> 6, lane = tid & 63;
    const int l16 = lane & 15, qd = lane >> 4;

    const int id  = blockIdx.y * 24 + blockIdx.x;       // 0..767
    const int xcd = id & 7, j = id >> 3;                // j 0..95
    const int m0 = (xcd * 4 + (j & 3)) * 128;           // 32 m-tiles
    const int n0 = (j >> 2) * 128;                      // 24 n-tiles

    const int mh = (wave >> 1) * 64, nh = (wave & 1) * 64;

    const int lrow = lane >> 3;
    const int cgw  = (lane & 7) ^ lrow;            // DMA global col-group swizzle
    const int cg0  = (qd ^ (l16 & 7)) * 8;         // frag col offset, ks=0
    const int cg1  = ((4 | qd) ^ (l16 & 7)) * 8;   // ks=1

    floatx4 acc[4][4];
    #pragma unroll
    for (int mi = 0; mi < 4; mi++)
        #pragma unroll
        for (int ni = 0; ni < 4; ni++)
            acc[mi][ni] = (floatx4){0.f, 0.f, 0.f, 0.f};

    size_t gA[4], gB[4];
    int lofs[4];
    #pragma unroll
    for (int jj = 0; jj < 4; jj++) {
        const int rb = wave * 32 + jj * 8;
        gA[jj] = (size_t)(m0 + rb + lrow) * DM + cgw * 8;
        gB[jj] = (size_t)(n0 + rb + lrow) * DM + cgw * 8;
        lofs[jj] = rb * 64;
    }

    #pragma unroll
    for (int jj = 0; jj < 4; jj++) {
        dma16(xb + gA[jj], &At[0][lofs[jj]]);
        dma16(wt + gB[jj], &Bt[0][lofs[jj]]);
    }

    for (int k0 = 0; k0 < DM; k0 += 64) {
        const int cur = (k0 >> 6) & 1;
        __syncthreads();
        if (k0 + 64 < DM) {
            #pragma unroll
            for (int jj = 0; jj < 4; jj++) {
                dma16(xb + gA[jj] + k0 + 64, &At[cur ^ 1][lofs[jj]]);
                dma16(wt + gB[jj] + k0 + 64, &Bt[cur ^ 1][lofs[jj]]);
            }
        }
        #pragma unroll
        for (int ks = 0; ks < 2; ks++) {
            const int cg = ks ? cg1 : cg0;
            shortx8 af[4], bfr[4];
            #pragma unroll
            for (int i = 0; i < 4; i++) {
                af[i]  = *(const shortx8*)&At[cur][(mh + i * 16 + l16) * 64 + cg];
                bfr[i] = *(const shortx8*)&Bt[cur][(nh + i * 16 + l16) * 64 + cg];
            }
            #pragma unroll
            for (int mi = 0; mi < 4; mi++)
                #pragma unroll
                for (int ni = 0; ni < 4; ni++)
                    acc[mi][ni] = __builtin_amdgcn_mfma_f32_16x16x32_bf16(
                        af[mi], bfr[ni], acc[mi][ni], 0, 0, 0);
        }
    }

    int ncol, H; unsigned short* dst; float sc; bool vtrans;
    if (n0 < 2048)      { ncol = n0;        dst = Qws; H = NQH;  sc = 0.125f * 1.44269504f; vtrans = false; }
    else if (n0 < 2560) { ncol = n0 - 2048; dst = Kws; H = NKVH; sc = 1.0f; vtrans = false; }
    else                { ncol = n0 - 2560; dst = Vws; H = NKVH; sc = 1.0f; vtrans = true;  }

    #pragma unroll
    for (int mi = 0; mi < 4; mi++)
        #pragma unroll
        for (int ni = 0; ni < 4; ni++)
            #pragma unroll
            for (int r = 0; r < 4; r++) {
                int m  = m0 + mh + mi * 16 + qd * 4 + r;
                int nc = ncol + nh + ni * 16 + l16;
                int b  = m >> 11, t = m & (T_SEQ - 1);
                int hh = nc >> 6, d = nc & 63;
                float v = acc[mi][ni][r] * sc;
                size_t idx = vtrans
                    ? ((((size_t)b * H + hh) * HD + d) << 11) + t
                    : ((((size_t)b * H + hh) * T_SEQ + t) << 6) + d;
                dst[idx] = f2bf(v);
            }
}

// ---------------------------------------------------------------------------
// Causal GQA flash attention, TRANSPOSED form: S^T = K Q^T, O^T = V^T P^T
// (operand-swapped MFMAs; all fragment reads identical to natural form).
// Gains: P-spill is 4 consecutive keys/lane -> b64 writes; lsum is 4 regs
// with 2-shuffle reduce; epilogue is float4 stores; inv lane-local.
// Block = (qt, kh, b), 4 waves = 4 q-heads sharing K/V. Double-buffered
// chunks, one barrier each. qt = z ? x : 31-x pairs co-resident blocks to
// a uniform 33-chunk makespan.
// ---------------------------------------------------------------------------
__global__ __launch_bounds__(256, 2) void attn_fwd(
    const unsigned short* __restrict__ Qws,
    const unsigned short* __restrict__ Kws,
    const unsigned short* __restrict__ Vtws,
    float* __restrict__ out)
{
    __shared__ __align__(16) unsigned short Ks[2][64 * 64];
    __shared__ __align__(16) unsigned short Vt[2][64 * 64];
    __shared__ __align__(16) unsigned short Ps[4][64][40];   // [q][key in 32-window]

    const int tid = threadIdx.x;
    const int wave = tid >> 6, lane = tid & 63;
    const int l16 = lane & 15, qd = lane >> 4;
    const int b = blockIdx.z;
    const int qt = b ? blockIdx.x : (31 - blockIdx.x);   // CU-pair makespan balance
    const int kh = blockIdx.y;
    const int h = kh * 4 + wave;
    const int q0 = qt * 64;

    const size_t qbase  = (((size_t)b * NQH + h) * T_SEQ + q0) * HD;
    const size_t kbase  = ((size_t)b * NKVH + kh) * (size_t)T_SEQ * HD;
    const size_t vtbase = ((size_t)b * NKVH + kh) * (size_t)HD * T_SEQ;

    // Q fragments (B operand; same bytes as A-layout reads), regs for whole block
    shortx8 qfr[4][2];
    #pragma unroll
    for (int mqt = 0; mqt < 4; mqt++)
        #pragma unroll
        for (int ks = 0; ks < 2; ks++)
            qfr[mqt][ks] = *(const shortx8*)(Qws + qbase +
                (size_t)(mqt * 16 + l16) * HD + ks * 32 + qd * 8);

    floatx4 oaccT[4][4];      // [mqt][dt]: O^T tile, col q = l16, rows d = qd*4+r
    #pragma unroll
    for (int mqt = 0; mqt < 4; mqt++)
        #pragma unroll
        for (int dt = 0; dt < 4; dt++)
            oaccT[mqt][dt] = (floatx4){0.f, 0.f, 0.f, 0.f};
    float lsum[4] = {0.f, 0.f, 0.f, 0.f};   // per-lane partial row-sum, q = mqt*16+l16

    const int lrow = lane >> 3;
    const int cgw  = (lane & 7) ^ lrow;
    const int xr   = l16 & 7;

    // prologue: stage chunk 0 into buffer 0
    #pragma unroll
    for (int j2 = 0; j2 < 2; j2++) {
        const int rb = wave * 16 + j2 * 8;
        dma16(Kws  + kbase  + (size_t)(rb + lrow) * HD + cgw * 8, &Ks[0][rb * 64]);
        dma16(Vtws + vtbase + (size_t)(rb + lrow) * T_SEQ + cgw * 8, &Vt[0][rb * 64]);
    }

    for (int c = 0; c <= qt; c++) {
        const int cur = c & 1;
        const int j0 = c * 64;
        __syncthreads();          // chunk c landed; buffer cur^1 free
        if (c < qt) {
            const int j0n = j0 + 64;
            #pragma unroll
            for (int j2 = 0; j2 < 2; j2++) {
                const int rb = wave * 16 + j2 * 8;
                dma16(Kws  + kbase  + (size_t)(j0n + rb + lrow) * HD + cgw * 8,
                      &Ks[cur ^ 1][rb * 64]);
                dma16(Vtws + vtbase + (size_t)(rb + lrow) * T_SEQ + j0n + cgw * 8,
                      &Vt[cur ^ 1][rb * 64]);
            }
        }

        const bool diag = (c == qt);

        #pragma unroll
        for (int kp = 0; kp < 2; kp++) {
            // K fragments (A operand) for this 32-key window
            shortx8 kf[2][2];
            #pragma unroll
            for (int ktl = 0; ktl < 2; ktl++) {
                const int krow = ((kp * 2 + ktl) * 16 + l16) * 64;
                kf[ktl][0] = *(const shortx8*)&Ks[cur][krow + ((qd ^ xr) * 8)];
                kf[ktl][1] = *(const shortx8*)&Ks[cur][krow + (((4 | qd) ^ xr) * 8)];
            }

            // ---- S^T = K Q^T, P = 2^S (truncated bf16), spill b64 ----
            #pragma unroll
            for (int ktl = 0; ktl < 2; ktl++) {
                #pragma unroll
                for (int mqt = 0; mqt < 4; mqt++) {
                    floatx4 s = (floatx4){0.f, 0.f, 0.f, 0.f};
                    s = __builtin_amdgcn_mfma_f32_16x16x32_bf16(kf[ktl][0], qfr[mqt][0], s, 0, 0, 0);
                    s = __builtin_amdgcn_mfma_f32_16x16x32_bf16(kf[ktl][1], qfr[mqt][1], s, 0, 0, 0);
                    unsigned int pu[4];
                    if (diag) {
                        const int qrel = mqt * 16 + l16;
                        const int jbase = kp * 32 + ktl * 16 + qd * 4;
                        #pragma unroll
                        for (int r = 0; r < 4; r++) {
                            float pe = EXP2F(s[r]);
                            unsigned int u = __builtin_bit_cast(unsigned int, pe) & 0xFFFF0000u;
                            if (jbase + r > qrel) u = 0u;
                            pu[r] = u;
                            lsum[mqt] += __builtin_bit_cast(float, u);
                        }
                    } else {
                        #pragma unroll
                        for (int r = 0; r < 4; r++) {
                            float pe = EXP2F(s[r]);
                            unsigned int u = __builtin_bit_cast(unsigned int, pe) & 0xFFFF0000u;
                            pu[r] = u;
                            lsum[mqt] += __builtin_bit_cast(float, u);
                        }
                    }
                    uint2 dw;
                    dw.x = (pu[0] >> 16) | (pu[1] & 0xFFFF0000u);
                    dw.y = (pu[2] >> 16) | (pu[3] & 0xFFFF0000u);
                    *(uint2*)&Ps[wave][mqt * 16 + l16][ktl * 16 + qd * 4] = dw;
                }
            }

            // ---- P^T fragments (B operand; same-wave LDS round trip) ----
            shortx8 pfr[4];
            #pragma unroll
            for (int mqt = 0; mqt < 4; mqt++)
                pfr[mqt] = *(const shortx8*)&Ps[wave][mqt * 16 + l16][qd * 8];

            // ---- O^T += V^T P^T ----
            #pragma unroll
            for (int dt = 0; dt < 4; dt++) {
                const shortx8 vf = *(const shortx8*)
                    &Vt[cur][(dt * 16 + l16) * 64 + (((kp * 4 + qd) ^ xr) * 8)];
                #pragma unroll
                for (int mqt = 0; mqt < 4; mqt++)
                    oaccT[mqt][dt] = __builtin_amdgcn_mfma_f32_16x16x32_bf16(
                        vf, pfr[mqt], oaccT[mqt][dt], 0, 0, 0);
            }
        }
    }

    // ---- row-sum: lanes {l16, l16+16, l16+32, l16+48} hold disjoint key sets ----
    float inv[4];
    #pragma unroll
    for (int mqt = 0; mqt < 4; mqt++) {
        float s = lsum[mqt];
        s += __shfl_xor(s, 16, 64);
        s += __shfl_xor(s, 32, 64);
        inv[mqt] = 1.f / s;
    }

    // ---- epilogue: O^T C-layout (col q = l16, rows d = qd*4+r) -> float4 ----
    #pragma unroll
    for (int mqt = 0; mqt < 4; mqt++) {
        const int t = q0 + mqt * 16 + l16;
        float* orow = out + ((size_t)b * T_SEQ + t) * (NQH * HD) + h * HD + qd * 4;
        #pragma unroll
        for (int dt = 0; dt < 4; dt++) {
            float4 o;
            o.x = oaccT[mqt][dt][0] * inv[mqt];
            o.y = oaccT[mqt][dt][1] * inv[mqt];
            o.z = oaccT[mqt][dt][2] * inv[mqt];
            o.w = oaccT[mqt][dt][3] * inv[mqt];
            *(float4*)(orow + dt * 16) = o;
        }
    }
}

extern "C" void kernel_launch(void* const* d_in, const int* in_sizes, int n_in,
                              void* d_out, int out_size, void* d_ws, size_t ws_size,
                              hipStream_t stream) {
    const float* x  = (const float*)d_in[0];
    const float* Wq = (const float*)d_in[1];
    const float* Wk = (const float*)d_in[2];
    const float* Wv = (const float*)d_in[3];
    float* out = (float*)d_out;

    // xb scratch lives in d_out (16.8 MB of 33.5 MB) — dead before attn writes.
    unsigned short* xb  = (unsigned short*)d_out;
    unsigned short* wt  = (unsigned short*)d_ws;                  // 12.6 MB
    unsigned short* Qws = wt  + (size_t)NTOT * DM;                // 16.8 MB
    unsigned short* Kws = Qws + (size_t)2 * NQH * T_SEQ * HD;     // 4.2 MB
    unsigned short* Vws = Kws + (size_t)2 * NKVH * T_SEQ * HD;    // 4.2 MB

    cvt_fused<<<4096 + 1536, 256, 0, stream>>>(x, Wq, Wk, Wv, xb, wt);
    qkv_gemm <<<dim3(24, 32), 256, 0, stream>>>(xb, wt, Qws, Kws, Vws);
    attn_fwd <<<dim3(32, NKVH, 2), 256, 0, stream>>>(Qws, Kws, Vws, out);
}